// Round 4
// baseline (5565.035 us; speedup 1.0000x reference)
//
#include <hip/hip_runtime.h>

#define DM     512
#define LAT    128
#define WIN_   256
#define ENC    55
#define GD     8          // d-slices per batch group (blocks that must sync)
#define GB     32         // batch groups
#define BT     8          // batch rows per group
#define DS     64         // h-dims per slice
#define NG     192        // gate rows per block (3*DS)
#define TPB    768        // 12 waves
#define OUT_T  256

typedef __attribute__((ext_vector_type(8))) short bf8;
typedef __attribute__((ext_vector_type(4))) float f4;
typedef unsigned long long u64;
typedef unsigned short u16;

// Scratch in module .bss: zero-initialized at load, not poisoned by the harness,
// no ws_size limit. (Rounds 1-3 NaN root cause was reading fp32 inputs as bf16,
// NOT scratch placement — but .bss remains the safest home for the ring.)
__device__ __align__(128) u64 g_ring[2 * 256 * 128];  // [2][256][512] bf16 = 512 KB
__device__ __align__(128) u64 g_bar[GB * 16];         // 32 groups, 128 B apart

__device__ __forceinline__ u16 f2bf(float f) {
    union { float f; unsigned int i; } v; v.f = f;
    unsigned int r = v.i + 0x7fffu + ((v.i >> 16) & 1u);
    return (u16)(r >> 16);
}
__device__ __forceinline__ float sigm(float x) { return 1.f / (1.f + __expf(-x)); }
__device__ __forceinline__ float tanh_(float x) {
    x = fminf(x, 40.f);
    float e = __expf(2.f * x);
    return (e - 1.f) / (e + 1.f);
}

// Persistent fused GRU+projection. 256 blocks = 32 batch-groups x 8 d-slices;
// 1 block/CU so all co-resident (group barrier can't deadlock).
// fp32 I/O per the reference; bf16 only inside MFMA fragments.
// Barrier counters are MONOTONIC across launches: each launch adds 257*8=2056
// (mult of 8) per group; at entry siblings can be at most +7 ahead (they can't
// pass barrier 1 without us), so base = load(cnt) & ~7 is the launch-start value.
__global__ __launch_bounds__(TPB, 3) void gru_fused(
    const float* __restrict__ z,    // [256][128]
    const float* __restrict__ hpw,  // [512][128]
    const float* __restrict__ hpb,  // [512]
    const float* __restrict__ whh,  // [1536][512]
    const float* __restrict__ bih,  // [1536]
    const float* __restrict__ bhh,  // [1536]
    const float* __restrict__ outw, // [55][512]
    const float* __restrict__ outb, // [55]
    float* __restrict__ out)        // [256][256][55] fp32
{
    const int blk  = blockIdx.x;
    const int g    = blk & (GB - 1);
    const int s    = blk >> 5;
    const int d0   = s * DS;
    const int row0 = g * BT;
    const int tid  = threadIdx.x;
    const int wave = tid >> 6;
    const int lane = tid & 63;
    const int quad = lane >> 4;
    const int nl   = lane & 15;

    __shared__ __align__(16) float gh[NG][12];  // [gate_local][batch], stride 12
    __shared__ float bias_r[DS], bias_z[DS], gin[DS], bhn[DS];
    __shared__ float hcur[2][BT][DS];           // fp32 h double-buffer (own slice)
    __shared__ u64 sh_base;

    u64* cnt = g_bar + g * 16;
    if (tid == 0)
        sh_base = __hip_atomic_load(cnt, __ATOMIC_RELAXED, __HIP_MEMORY_SCOPE_AGENT)
                  & ~7ULL;

    if (tid < DS) {
        int dg = d0 + tid;
        bias_r[tid] = bih[dg]       + bhh[dg];
        bias_z[tid] = bih[512 + dg] + bhh[512 + dg];
        gin[tid]    = bih[1024 + dg];
        bhn[tid]    = bhh[1024 + dg];
    }

    // Resident B-fragments: this wave's 16 gate rows x K=512 (fp32 -> bf16 once).
    const int gl   = wave * 16 + nl;
    const int sel  = gl >> 6;
    const int jrow = sel * 512 + d0 + (gl & 63);
    bf8 bfrag[16];
#pragma unroll
    for (int kb = 0; kb < 16; ++kb) {
        const float* wp = whh + jrow * DM + kb * 32 + quad * 8;
        bf8 v;
#pragma unroll
        for (int j = 0; j < 8; ++j) v[j] = (short)f2bf(wp[j]);
        bfrag[kb] = v;
    }

    // h0 = tanh(z @ hpw^T + hpb), fp32 into hcur[0]
    if (tid < BT * DS) {
        int d = tid & (DS - 1), bl = tid >> 6;
        float acc = hpb[d0 + d];
        const float* zr = z + (row0 + bl) * LAT;
        const float* wr = hpw + (d0 + d) * LAT;
#pragma unroll 8
        for (int k = 0; k < LAT; ++k) acc += zr[k] * wr[k];
        hcur[0][bl][d] = tanh_(acc);
    }
    __syncthreads();

    u64 tgt = sh_base;

    // ---- store h(0) slice to ring slot 0 + group barrier ----
    {
        if (tid < 128) {
            int bl = tid >> 4, idx = tid & 15;
            const float* hv = &hcur[0][bl][idx * 4];
            u64 v = (u64)f2bf(hv[0]) | ((u64)f2bf(hv[1]) << 16) |
                    ((u64)f2bf(hv[2]) << 32) | ((u64)f2bf(hv[3]) << 48);
            u64* dst = g_ring + (u64)(row0 + bl) * 128 + (d0 >> 2) + idx;
            __hip_atomic_store(dst, v, __ATOMIC_RELAXED, __HIP_MEMORY_SCOPE_AGENT);
            __threadfence();  // stores at PoC before barrier arrival
        }
        __syncthreads();
        tgt += GD;
        if (tid == 0) {
            __hip_atomic_fetch_add(cnt, 1ULL, __ATOMIC_RELAXED, __HIP_MEMORY_SCOPE_AGENT);
            long guard = 0;
            while (__hip_atomic_load(cnt, __ATOMIC_RELAXED, __HIP_MEMORY_SCOPE_AGENT) < tgt &&
                   guard < (1L << 20)) { __builtin_amdgcn_s_sleep(2); ++guard; }
        }
        __syncthreads();
    }

    // A-fragment u64 base per lane: row = batch row (nl&7), dims quad*8 + kb*32
    const int  arow = row0 + (nl & 7);
    const u64* ap0  = g_ring + (u64)arow * 128 + quad * 2;          // slot 0
    const u64* ap1  = g_ring + (u64)(256 + arow) * 128 + quad * 2;  // slot 1

    for (int t = 1; t <= WIN_; ++t) {
        const int sp = (t - 1) & 1, sc = t & 1;
        const u64* ap = sp ? ap1 : ap0;

        // load full A tile (8 batch rows x 512 dims) as 32 PoC u64 loads/lane
        bf8 a[16];
#pragma unroll
        for (int kb = 0; kb < 16; ++kb) {
            u64 lo = __hip_atomic_load(ap + kb * 8,     __ATOMIC_RELAXED, __HIP_MEMORY_SCOPE_AGENT);
            u64 hi = __hip_atomic_load(ap + kb * 8 + 1, __ATOMIC_RELAXED, __HIP_MEMORY_SCOPE_AGENT);
            union { u64 q[2]; bf8 v; } u; u.q[0] = lo; u.q[1] = hi;
            a[kb] = u.v;
        }

        f4 acc = {0.f, 0.f, 0.f, 0.f};
#pragma unroll
        for (int kb = 0; kb < 16; ++kb)
            acc = __builtin_amdgcn_mfma_f32_16x16x32_bf16(a[kb], bfrag[kb], acc, 0, 0, 0);

        // fused projection burst: out[:, tau, :] = h(tau+1) @ outw^T + outb
        const int tau = t - 2;
        if (tau >= 0 && ((tau & 7) == s) && wave < 4) {
            const int e  = wave * 16 + nl;
            const int ec = (e < ENC) ? e : (ENC - 1);
            const float* wp = outw + ec * DM + quad * 8;
            f4 accp = {0.f, 0.f, 0.f, 0.f};
#pragma unroll
            for (int kb = 0; kb < 16; ++kb) {
                bf8 wv;
#pragma unroll
                for (int j = 0; j < 8; ++j) wv[j] = (short)f2bf(wp[kb * 32 + j]);
                accp = __builtin_amdgcn_mfma_f32_16x16x32_bf16(a[kb], wv, accp, 0, 0, 0);
            }
            if (quad < 2 && e < ENC) {
                float ob = outb[ec];
#pragma unroll
                for (int r = 0; r < 4; ++r) {
                    int m = quad * 4 + r;
                    out[(row0 + m) * (OUT_T * ENC) + tau * ENC + e] = accp[r] + ob;
                }
            }
        }

        // D[m=quad*4+r][n=nl]; keep only m<8 (real batch rows)
        if (quad < 2) *(f4*)&gh[gl][quad * 4] = acc;
        __syncthreads();

        if (tid < BT * DS) {
            int ed = tid & (DS - 1), ebl = tid >> 6;
            float hp = hcur[sp][ebl][ed];
            float r  = sigm(bias_r[ed] + gh[ed][ebl]);
            float zg = sigm(bias_z[ed] + gh[64 + ed][ebl]);
            float n  = tanh_(gin[ed] + r * (bhn[ed] + gh[128 + ed][ebl]));
            hcur[sc][ebl][ed] = (1.f - zg) * n + zg * hp;
        }
        __syncthreads();

        if (tid < 128) {
            int bl = tid >> 4, idx = tid & 15;
            const float* hv = &hcur[sc][bl][idx * 4];
            u64 v = (u64)f2bf(hv[0]) | ((u64)f2bf(hv[1]) << 16) |
                    ((u64)f2bf(hv[2]) << 32) | ((u64)f2bf(hv[3]) << 48);
            u64* dst = g_ring + (u64)(sc * 256 + row0 + bl) * 128 + (d0 >> 2) + idx;
            __hip_atomic_store(dst, v, __ATOMIC_RELAXED, __HIP_MEMORY_SCOPE_AGENT);
            __threadfence();
        }
        __syncthreads();
        tgt += GD;
        if (tid == 0) {
            __hip_atomic_fetch_add(cnt, 1ULL, __ATOMIC_RELAXED, __HIP_MEMORY_SCOPE_AGENT);
            long guard = 0;
            while (__hip_atomic_load(cnt, __ATOMIC_RELAXED, __HIP_MEMORY_SCOPE_AGENT) < tgt &&
                   guard < (1L << 20)) { __builtin_amdgcn_s_sleep(2); ++guard; }
        }
        __syncthreads();
    }

    // tail: tau=255 uses h(256) (ring slot 0, published by the t=256 barrier)
    if (s == 7 && wave < 4) {
        bf8 a[16];
#pragma unroll
        for (int kb = 0; kb < 16; ++kb) {
            u64 lo = __hip_atomic_load(ap0 + kb * 8,     __ATOMIC_RELAXED, __HIP_MEMORY_SCOPE_AGENT);
            u64 hi = __hip_atomic_load(ap0 + kb * 8 + 1, __ATOMIC_RELAXED, __HIP_MEMORY_SCOPE_AGENT);
            union { u64 q[2]; bf8 v; } u; u.q[0] = lo; u.q[1] = hi;
            a[kb] = u.v;
        }
        const int e  = wave * 16 + nl;
        const int ec = (e < ENC) ? e : (ENC - 1);
        const float* wp = outw + ec * DM + quad * 8;
        f4 accp = {0.f, 0.f, 0.f, 0.f};
#pragma unroll
        for (int kb = 0; kb < 16; ++kb) {
            bf8 wv;
#pragma unroll
            for (int j = 0; j < 8; ++j) wv[j] = (short)f2bf(wp[kb * 32 + j]);
            accp = __builtin_amdgcn_mfma_f32_16x16x32_bf16(a[kb], wv, accp, 0, 0, 0);
        }
        if (quad < 2 && e < ENC) {
            float ob = outb[ec];
#pragma unroll
            for (int r = 0; r < 4; ++r) {
                int m = quad * 4 + r;
                out[(row0 + m) * (OUT_T * ENC) + 255 * ENC + e] = accp[r] + ob;
            }
        }
    }
}

extern "C" void kernel_launch(void* const* d_in, const int* in_sizes, int n_in,
                              void* d_out, int out_size, void* d_ws, size_t ws_size,
                              hipStream_t stream) {
    const float* z    = (const float*)d_in[0];
    const float* hpw  = (const float*)d_in[1];
    const float* hpb  = (const float*)d_in[2];
    // d_in[3] = w_ih: unused by the reference (input gates are pure biases)
    const float* whh  = (const float*)d_in[4];
    const float* bih  = (const float*)d_in[5];
    const float* bhh  = (const float*)d_in[6];
    const float* outw = (const float*)d_in[7];
    const float* outb = (const float*)d_in[8];
    float* out = (float*)d_out;

    (void)d_ws; (void)ws_size;  // scratch lives in module .bss
    gru_fused<<<dim3(256), dim3(TPB), 0, stream>>>(
        z, hpw, hpb, whh, bih, bhh, outw, outb, out);
}

// Round 5
// 3975.845 us; speedup vs baseline: 1.3997x; 1.3997x over previous
//
#include <hip/hip_runtime.h>

#define DM     512
#define LAT    128
#define WIN_   256
#define ENC    55
#define GD     8          // d-slices per batch group (blocks that must sync)
#define GB     32         // batch groups
#define BT     8          // batch rows per group
#define DS     64         // h-dims per slice
#define NG     192        // gate rows per block (3*DS)
#define TPB    768        // 12 waves
#define OUT_T  256

typedef __attribute__((ext_vector_type(8))) short bf8;
typedef __attribute__((ext_vector_type(4))) float f4;
typedef unsigned long long u64;
typedef unsigned short u16;

// Scratch in module .bss: zero-initialized at load, not poisoned by the harness.
__device__ __align__(128) u64 g_ring[2 * 256 * 128];  // [2][256][512] bf16 = 512 KB
__device__ __align__(128) u64 g_bar[GB * 16];         // 32 groups, 128 B apart

__device__ __forceinline__ u16 f2bf(float f) {
    union { float f; unsigned int i; } v; v.f = f;
    unsigned int r = v.i + 0x7fffu + ((v.i >> 16) & 1u);
    return (u16)(r >> 16);
}
__device__ __forceinline__ float sigm(float x) { return 1.f / (1.f + __expf(-x)); }
__device__ __forceinline__ float tanh_(float x) {
    x = fminf(x, 40.f);
    float e = __expf(2.f * x);
    return (e - 1.f) / (e + 1.f);
}

// Persistent fused GRU+projection. 256 blocks = 32 batch-groups x 8 d-slices;
// 1 block/CU so all co-resident. fp32 I/O; bf16 only inside MFMA fragments.
//
// Visibility without fences (R4 ran __threadfence per step -> per-XCD
// buffer_wbl2+inv storm = 21.5us/step): every ring access is an AGENT-scope
// relaxed u64 atomic, so producer stores and consumer loads share one
// coherence point. __syncthreads() drains vmcnt(0) in every wave before
// s_barrier, so all ring stores are complete at that point before tid 0
// issues the barrier add. No cache maintenance needed.
//
// Barrier counters are MONOTONIC across launches: each launch adds 257*8=2056
// per group; at entry siblings can be at most +7 ahead, so
// base = load(cnt) & ~7 recovers the launch-start value.
__global__ __launch_bounds__(TPB, 3) void gru_fused(
    const float* __restrict__ z,    // [256][128]
    const float* __restrict__ hpw,  // [512][128]
    const float* __restrict__ hpb,  // [512]
    const float* __restrict__ whh,  // [1536][512]
    const float* __restrict__ bih,  // [1536]
    const float* __restrict__ bhh,  // [1536]
    const float* __restrict__ outw, // [55][512]
    const float* __restrict__ outb, // [55]
    float* __restrict__ out)        // [256][256][55] fp32
{
    const int blk  = blockIdx.x;
    const int g    = blk & (GB - 1);
    const int s    = blk >> 5;
    const int d0   = s * DS;
    const int row0 = g * BT;
    const int tid  = threadIdx.x;
    const int wave = tid >> 6;
    const int lane = tid & 63;
    const int quad = lane >> 4;
    const int nl   = lane & 15;

    __shared__ __align__(16) float gh[NG][12];  // [gate_local][batch], stride 12
    __shared__ float bias_r[DS], bias_z[DS], gin[DS], bhn[DS];
    __shared__ float hcur[2][BT][DS];           // fp32 h double-buffer (own slice)
    __shared__ u64 sh_base;

    u64* cnt = g_bar + g * 16;
    if (tid == 0)
        sh_base = __hip_atomic_load(cnt, __ATOMIC_RELAXED, __HIP_MEMORY_SCOPE_AGENT)
                  & ~7ULL;

    if (tid < DS) {
        int dg = d0 + tid;
        bias_r[tid] = bih[dg]       + bhh[dg];
        bias_z[tid] = bih[512 + dg] + bhh[512 + dg];
        gin[tid]    = bih[1024 + dg];
        bhn[tid]    = bhh[1024 + dg];
    }

    // Resident B-fragments: this wave's 16 gate rows x K=512 (fp32 -> bf16 once).
    const int gl   = wave * 16 + nl;
    const int sel  = gl >> 6;
    const int jrow = sel * 512 + d0 + (gl & 63);
    bf8 bfrag[16];
#pragma unroll
    for (int kb = 0; kb < 16; ++kb) {
        const float* wp = whh + jrow * DM + kb * 32 + quad * 8;
        bf8 v;
#pragma unroll
        for (int j = 0; j < 8; ++j) v[j] = (short)f2bf(wp[j]);
        bfrag[kb] = v;
    }

    // h0 = tanh(z @ hpw^T + hpb), fp32 into hcur[0]
    if (tid < BT * DS) {
        int d = tid & (DS - 1), bl = tid >> 6;
        float acc = hpb[d0 + d];
        const float* zr = z + (row0 + bl) * LAT;
        const float* wr = hpw + (d0 + d) * LAT;
#pragma unroll 8
        for (int k = 0; k < LAT; ++k) acc += zr[k] * wr[k];
        hcur[0][bl][d] = tanh_(acc);
    }
    __syncthreads();

    u64 tgt = sh_base;

    // ---- store h(0) slice to ring slot 0 + group barrier ----
    {
        if (tid < 128) {
            int bl = tid >> 4, idx = tid & 15;
            const float* hv = &hcur[0][bl][idx * 4];
            u64 v = (u64)f2bf(hv[0]) | ((u64)f2bf(hv[1]) << 16) |
                    ((u64)f2bf(hv[2]) << 32) | ((u64)f2bf(hv[3]) << 48);
            u64* dst = g_ring + (u64)(row0 + bl) * 128 + (d0 >> 2) + idx;
            __hip_atomic_store(dst, v, __ATOMIC_RELAXED, __HIP_MEMORY_SCOPE_AGENT);
        }
        __syncthreads();  // drains vmcnt(0) per wave: ring stores complete
        tgt += GD;
        if (tid == 0) {
            __hip_atomic_fetch_add(cnt, 1ULL, __ATOMIC_RELAXED, __HIP_MEMORY_SCOPE_AGENT);
            long guard = 0;
            while (__hip_atomic_load(cnt, __ATOMIC_RELAXED, __HIP_MEMORY_SCOPE_AGENT) < tgt &&
                   guard < (1L << 20)) { __builtin_amdgcn_s_sleep(2); ++guard; }
        }
        __syncthreads();
    }

    // A-fragment u64 base per lane: row = batch row (nl&7), dims quad*8 + kb*32
    const int  arow = row0 + (nl & 7);
    const u64* ap0  = g_ring + (u64)arow * 128 + quad * 2;          // slot 0
    const u64* ap1  = g_ring + (u64)(256 + arow) * 128 + quad * 2;  // slot 1

    for (int t = 1; t <= WIN_; ++t) {
        const int sp = (t - 1) & 1, sc = t & 1;
        const u64* ap = sp ? ap1 : ap0;

        // load full A tile (8 batch rows x 512 dims) as 32 PoC u64 loads/lane
        bf8 a[16];
#pragma unroll
        for (int kb = 0; kb < 16; ++kb) {
            u64 lo = __hip_atomic_load(ap + kb * 8,     __ATOMIC_RELAXED, __HIP_MEMORY_SCOPE_AGENT);
            u64 hi = __hip_atomic_load(ap + kb * 8 + 1, __ATOMIC_RELAXED, __HIP_MEMORY_SCOPE_AGENT);
            union { u64 q[2]; bf8 v; } u; u.q[0] = lo; u.q[1] = hi;
            a[kb] = u.v;
        }

        f4 acc = {0.f, 0.f, 0.f, 0.f};
#pragma unroll
        for (int kb = 0; kb < 16; ++kb)
            acc = __builtin_amdgcn_mfma_f32_16x16x32_bf16(a[kb], bfrag[kb], acc, 0, 0, 0);

        // fused projection burst: out[:, tau, :] = h(tau+1) @ outw^T + outb
        const int tau = t - 2;
        if (tau >= 0 && ((tau & 7) == s) && wave < 4) {
            const int e  = wave * 16 + nl;
            const int ec = (e < ENC) ? e : (ENC - 1);
            const float* wp = outw + ec * DM + quad * 8;
            f4 accp = {0.f, 0.f, 0.f, 0.f};
#pragma unroll
            for (int kb = 0; kb < 16; ++kb) {
                bf8 wv;
#pragma unroll
                for (int j = 0; j < 8; ++j) wv[j] = (short)f2bf(wp[kb * 32 + j]);
                accp = __builtin_amdgcn_mfma_f32_16x16x32_bf16(a[kb], wv, accp, 0, 0, 0);
            }
            if (quad < 2 && e < ENC) {
                float ob = outb[ec];
#pragma unroll
                for (int r = 0; r < 4; ++r) {
                    int m = quad * 4 + r;
                    out[(row0 + m) * (OUT_T * ENC) + tau * ENC + e] = accp[r] + ob;
                }
            }
        }

        // D[m=quad*4+r][n=nl]; keep only m<8 (real batch rows)
        if (quad < 2) *(f4*)&gh[gl][quad * 4] = acc;
        __syncthreads();

        if (tid < BT * DS) {
            int ed = tid & (DS - 1), ebl = tid >> 6;
            float hp = hcur[sp][ebl][ed];
            float r  = sigm(bias_r[ed] + gh[ed][ebl]);
            float zg = sigm(bias_z[ed] + gh[64 + ed][ebl]);
            float n  = tanh_(gin[ed] + r * (bhn[ed] + gh[128 + ed][ebl]));
            hcur[sc][ebl][ed] = (1.f - zg) * n + zg * hp;
        }
        __syncthreads();

        if (tid < 128) {
            int bl = tid >> 4, idx = tid & 15;
            const float* hv = &hcur[sc][bl][idx * 4];
            u64 v = (u64)f2bf(hv[0]) | ((u64)f2bf(hv[1]) << 16) |
                    ((u64)f2bf(hv[2]) << 32) | ((u64)f2bf(hv[3]) << 48);
            u64* dst = g_ring + (u64)(sc * 256 + row0 + bl) * 128 + (d0 >> 2) + idx;
            __hip_atomic_store(dst, v, __ATOMIC_RELAXED, __HIP_MEMORY_SCOPE_AGENT);
        }
        __syncthreads();  // drains vmcnt(0) per wave: ring stores complete
        tgt += GD;
        if (tid == 0) {
            __hip_atomic_fetch_add(cnt, 1ULL, __ATOMIC_RELAXED, __HIP_MEMORY_SCOPE_AGENT);
            long guard = 0;
            while (__hip_atomic_load(cnt, __ATOMIC_RELAXED, __HIP_MEMORY_SCOPE_AGENT) < tgt &&
                   guard < (1L << 20)) { __builtin_amdgcn_s_sleep(2); ++guard; }
        }
        __syncthreads();
    }

    // tail: tau=255 uses h(256) (ring slot 0, published by the t=256 barrier)
    if (s == 7 && wave < 4) {
        bf8 a[16];
#pragma unroll
        for (int kb = 0; kb < 16; ++kb) {
            u64 lo = __hip_atomic_load(ap0 + kb * 8,     __ATOMIC_RELAXED, __HIP_MEMORY_SCOPE_AGENT);
            u64 hi = __hip_atomic_load(ap0 + kb * 8 + 1, __ATOMIC_RELAXED, __HIP_MEMORY_SCOPE_AGENT);
            union { u64 q[2]; bf8 v; } u; u.q[0] = lo; u.q[1] = hi;
            a[kb] = u.v;
        }
        const int e  = wave * 16 + nl;
        const int ec = (e < ENC) ? e : (ENC - 1);
        const float* wp = outw + ec * DM + quad * 8;
        f4 accp = {0.f, 0.f, 0.f, 0.f};
#pragma unroll
        for (int kb = 0; kb < 16; ++kb) {
            bf8 wv;
#pragma unroll
            for (int j = 0; j < 8; ++j) wv[j] = (short)f2bf(wp[kb * 32 + j]);
            accp = __builtin_amdgcn_mfma_f32_16x16x32_bf16(a[kb], wv, accp, 0, 0, 0);
        }
        if (quad < 2 && e < ENC) {
            float ob = outb[ec];
#pragma unroll
            for (int r = 0; r < 4; ++r) {
                int m = quad * 4 + r;
                out[(row0 + m) * (OUT_T * ENC) + 255 * ENC + e] = accp[r] + ob;
            }
        }
    }
}

extern "C" void kernel_launch(void* const* d_in, const int* in_sizes, int n_in,
                              void* d_out, int out_size, void* d_ws, size_t ws_size,
                              hipStream_t stream) {
    const float* z    = (const float*)d_in[0];
    const float* hpw  = (const float*)d_in[1];
    const float* hpb  = (const float*)d_in[2];
    // d_in[3] = w_ih: unused by the reference (input gates are pure biases)
    const float* whh  = (const float*)d_in[4];
    const float* bih  = (const float*)d_in[5];
    const float* bhh  = (const float*)d_in[6];
    const float* outw = (const float*)d_in[7];
    const float* outb = (const float*)d_in[8];
    float* out = (float*)d_out;

    (void)d_ws; (void)ws_size;  // scratch lives in module .bss
    gru_fused<<<dim3(256), dim3(TPB), 0, stream>>>(
        z, hpw, hpb, whh, bih, bhh, outw, outb, out);
}

// Round 6
// 1656.465 us; speedup vs baseline: 3.3596x; 2.4002x over previous
//
#include <hip/hip_runtime.h>

#define DM     512
#define LAT    128
#define WIN_   256
#define ENC    55
#define GD     8          // d-slices per batch group (blocks that must sync)
#define GB     32         // batch groups
#define BT     8          // batch rows per group
#define DS     64         // h-dims per slice
#define NG     192        // gate rows per block (3*DS)
#define TPB    768        // 12 waves
#define OUT_T  256
#define AROWB  1056       // LDS bytes per A row (1024 data + 32 pad)

typedef __attribute__((ext_vector_type(8))) short bf8;
typedef __attribute__((ext_vector_type(4))) float f4;
typedef unsigned long long u64;
typedef unsigned short u16;

// Scratch in module .bss: zero-initialized at load, not poisoned by the harness.
__device__ __align__(128) u64 g_ring[2 * 256 * 128];  // [2][256][512] bf16 = 512 KB
__device__ __align__(128) u64 g_bar[GB * 16];         // 32 groups, 128 B apart

__device__ __forceinline__ u16 f2bf(float f) {
    union { float f; unsigned int i; } v; v.f = f;
    unsigned int r = v.i + 0x7fffu + ((v.i >> 16) & 1u);
    return (u16)(r >> 16);
}
__device__ __forceinline__ float sigm(float x) { return 1.f / (1.f + __expf(-x)); }
__device__ __forceinline__ float tanh_(float x) {
    x = fminf(x, 40.f);
    float e = __expf(2.f * x);
    return (e - 1.f) / (e + 1.f);
}

// Persistent fused GRU+projection. 256 blocks = 32 batch-groups x 8 d-slices.
// R5 was request-rate-bound: every wave loaded the 8 KB A-tile with per-lane
// 8-B atomic loads (24,576 L2 requests/block/step). Now the tile is staged to
// LDS once (~64 wide requests) and waves read fragments via ds_read_b128.
// Barrier: all waves spin on the group counter (same-addr load = 1 req/wave);
// ring stores drain via the s_waitcnt vmcnt(0) each wave executes before
// s_barrier, so the tid0 fetch_add after the barrier publishes complete data.
// Counters are MONOTONIC across launches (launch adds 257*8 per group; at
// entry siblings are at most +7 ahead, so base = load & ~7).
__global__ __launch_bounds__(TPB, 3) void gru_fused(
    const float* __restrict__ z,    // [256][128]
    const float* __restrict__ hpw,  // [512][128]
    const float* __restrict__ hpb,  // [512]
    const float* __restrict__ whh,  // [1536][512]
    const float* __restrict__ bih,  // [1536]
    const float* __restrict__ bhh,  // [1536]
    const float* __restrict__ outw, // [55][512]
    const float* __restrict__ outb, // [55]
    float* __restrict__ out)        // [256][256][55] fp32
{
    const int blk  = blockIdx.x;
    const int g    = blk & (GB - 1);
    const int s    = blk >> 5;
    const int d0   = s * DS;
    const int row0 = g * BT;
    const int tid  = threadIdx.x;
    const int wave = tid >> 6;
    const int lane = tid & 63;
    const int quad = lane >> 4;
    const int nl   = lane & 15;

    __shared__ __align__(16) unsigned char smemA[BT * AROWB];  // 8448 B staged h(t-1)
    __shared__ __align__(16) float gh[NG][12];                 // gate pre-acts
    __shared__ float bias_r[DS], bias_z[DS], gin[DS], bhn[DS];
    __shared__ float hcur[2][BT][DS];                          // fp32 h double-buffer
    __shared__ u64 sh_base;

    u64* cnt = g_bar + g * 16;
    if (tid == 0)
        sh_base = __hip_atomic_load(cnt, __ATOMIC_RELAXED, __HIP_MEMORY_SCOPE_AGENT)
                  & ~7ULL;

    if (tid < DS) {
        int dg = d0 + tid;
        bias_r[tid] = bih[dg]       + bhh[dg];
        bias_z[tid] = bih[512 + dg] + bhh[512 + dg];
        gin[tid]    = bih[1024 + dg];
        bhn[tid]    = bhh[1024 + dg];
    }

    // Resident B-fragments: this wave's 16 gate rows x K=512 (fp32 -> bf16 once).
    const int gl   = wave * 16 + nl;
    const int sel  = gl >> 6;
    const int jrow = sel * 512 + d0 + (gl & 63);
    bf8 bfrag[16];
#pragma unroll
    for (int kb = 0; kb < 16; ++kb) {
        const float* wp = whh + jrow * DM + kb * 32 + quad * 8;
        bf8 v;
#pragma unroll
        for (int j = 0; j < 8; ++j) v[j] = (short)f2bf(wp[j]);
        bfrag[kb] = v;
    }

    // h0 = tanh(z @ hpw^T + hpb), fp32 into hcur[0]
    if (tid < BT * DS) {
        int d = tid & (DS - 1), bl = tid >> 6;
        float acc = hpb[d0 + d];
        const float* zr = z + (row0 + bl) * LAT;
        const float* wr = hpw + (d0 + d) * LAT;
#pragma unroll 8
        for (int k = 0; k < LAT; ++k) acc += zr[k] * wr[k];
        hcur[0][bl][d] = tanh_(acc);
    }
    __syncthreads();

    u64 tgt = sh_base;

    // ---- publish h(0) slice to ring slot 0 ----
    if (tid < 128) {
        int bl = tid >> 4, c = tid & 15;
        const float* hv = &hcur[0][bl][c * 4];
        u64 v = (u64)f2bf(hv[0]) | ((u64)f2bf(hv[1]) << 16) |
                ((u64)f2bf(hv[2]) << 32) | ((u64)f2bf(hv[3]) << 48);
        u64* dst = g_ring + (u64)(row0 + bl) * 128 + (d0 >> 2) + c;
        __hip_atomic_store(dst, v, __ATOMIC_RELAXED, __HIP_MEMORY_SCOPE_AGENT);
    }
    __syncthreads();  // drains vmcnt(0) per wave: ring stores complete
    tgt += GD;
    if (tid == 0)
        __hip_atomic_fetch_add(cnt, 1ULL, __ATOMIC_RELAXED, __HIP_MEMORY_SCOPE_AGENT);

    const char* afrag_p = (const char*)smemA + (nl & 7) * AROWB + quad * 16;

    for (int t = 1; t <= WIN_; ++t) {
        const int sp = (t - 1) & 1, sc = t & 1;

        // all-wave spin: 64 same-addr lanes = 1 request per wave per poll
        {
            long guard = 0;
            while (__hip_atomic_load(cnt, __ATOMIC_RELAXED, __HIP_MEMORY_SCOPE_AGENT) < tgt &&
                   guard < (1L << 20)) { __builtin_amdgcn_s_sleep(2); ++guard; }
        }

        // stage h(t-1) tile (8 rows x 1 KB) into LDS: 512 threads x 2 u64
        if (tid < 512) {
            int r = tid >> 6, p = tid & 63;
            const u64* src = g_ring + (u64)(sp * 256 + row0 + r) * 128 + 2 * p;
            u64 lo = __hip_atomic_load(src,     __ATOMIC_RELAXED, __HIP_MEMORY_SCOPE_AGENT);
            u64 hi = __hip_atomic_load(src + 1, __ATOMIC_RELAXED, __HIP_MEMORY_SCOPE_AGENT);
            u64* lp = (u64*)(smemA + r * AROWB + p * 16);
            lp[0] = lo; lp[1] = hi;
        }
        __syncthreads();

        // fragments from LDS + MFMA (gate GEMM for this block's 192 rows)
        f4 acc = {0.f, 0.f, 0.f, 0.f};
#pragma unroll
        for (int kb = 0; kb < 16; ++kb) {
            bf8 av = *(const bf8*)(afrag_p + kb * 64);
            acc = __builtin_amdgcn_mfma_f32_16x16x32_bf16(av, bfrag[kb], acc, 0, 0, 0);
        }
        if (quad < 2) *(f4*)&gh[gl][quad * 4] = acc;  // D[m=quad*4+r][n=nl], m<8 real
        __syncthreads();

        // ---- parallel phase: gate update (waves 0-1) | projection (waves 4-7) ----
        if (tid < 128) {
            int bl = tid >> 4, c = tid & 15;
            float hn0, hn1, hn2, hn3;
            u64 v = 0;
            float* hpv = &hcur[sp][bl][c * 4];
            float* hnv = &hcur[sc][bl][c * 4];
#pragma unroll
            for (int j = 0; j < 4; ++j) {
                int d = c * 4 + j;
                float r  = sigm(bias_r[d] + gh[d][bl]);
                float zg = sigm(bias_z[d] + gh[64 + d][bl]);
                float n  = tanh_(gin[d] + r * (bhn[d] + gh[128 + d][bl]));
                float h  = (1.f - zg) * n + zg * hpv[j];
                hnv[j] = h;
                v |= (u64)f2bf(h) << (16 * j);
            }
            u64* dst = g_ring + (u64)(sc * 256 + row0 + bl) * 128 + (d0 >> 2) + c;
            __hip_atomic_store(dst, v, __ATOMIC_RELAXED, __HIP_MEMORY_SCOPE_AGENT);
            (void)hn0; (void)hn1; (void)hn2; (void)hn3;
        }

        const int tau = t - 2;  // projection uses h(tau+1) = staged tile
        if (tau >= 0 && ((tau & 7) == s) && wave >= 4 && wave < 8) {
            const int e  = (wave - 4) * 16 + nl;
            const int ec = (e < ENC) ? e : (ENC - 1);
            const float* wp = outw + ec * DM + quad * 8;
            f4 accp = {0.f, 0.f, 0.f, 0.f};
#pragma unroll
            for (int kb = 0; kb < 16; ++kb) {
                bf8 av = *(const bf8*)(afrag_p + kb * 64);
                bf8 wv;
#pragma unroll
                for (int j = 0; j < 8; ++j) wv[j] = (short)f2bf(wp[kb * 32 + j]);
                accp = __builtin_amdgcn_mfma_f32_16x16x32_bf16(av, wv, accp, 0, 0, 0);
            }
            if (quad < 2 && e < ENC) {
                float ob = outb[ec];
#pragma unroll
                for (int r = 0; r < 4; ++r) {
                    int m = quad * 4 + r;
                    out[(row0 + m) * (OUT_T * ENC) + tau * ENC + e] = accp[r] + ob;
                }
            }
        }

        __syncthreads();  // drains ring stores (and finishes projection) before add
        tgt += GD;
        if (tid == 0)
            __hip_atomic_fetch_add(cnt, 1ULL, __ATOMIC_RELAXED, __HIP_MEMORY_SCOPE_AGENT);
    }

    // ---- tail: tau=255 uses h(256) (ring slot 0, published by t=256 barrier) ----
    {
        long guard = 0;
        while (__hip_atomic_load(cnt, __ATOMIC_RELAXED, __HIP_MEMORY_SCOPE_AGENT) < tgt &&
               guard < (1L << 20)) { __builtin_amdgcn_s_sleep(2); ++guard; }
    }
    if (tid < 512) {
        int r = tid >> 6, p = tid & 63;
        const u64* src = g_ring + (u64)(row0 + r) * 128 + 2 * p;  // slot 0
        u64 lo = __hip_atomic_load(src,     __ATOMIC_RELAXED, __HIP_MEMORY_SCOPE_AGENT);
        u64 hi = __hip_atomic_load(src + 1, __ATOMIC_RELAXED, __HIP_MEMORY_SCOPE_AGENT);
        u64* lp = (u64*)(smemA + r * AROWB + p * 16);
        lp[0] = lo; lp[1] = hi;
    }
    __syncthreads();
    if (s == 7 && wave >= 4 && wave < 8) {
        const int e  = (wave - 4) * 16 + nl;
        const int ec = (e < ENC) ? e : (ENC - 1);
        const float* wp = outw + ec * DM + quad * 8;
        f4 accp = {0.f, 0.f, 0.f, 0.f};
#pragma unroll
        for (int kb = 0; kb < 16; ++kb) {
            bf8 av = *(const bf8*)(afrag_p + kb * 64);
            bf8 wv;
#pragma unroll
            for (int j = 0; j < 8; ++j) wv[j] = (short)f2bf(wp[kb * 32 + j]);
            accp = __builtin_amdgcn_mfma_f32_16x16x32_bf16(av, wv, accp, 0, 0, 0);
        }
        if (quad < 2 && e < ENC) {
            float ob = outb[ec];
#pragma unroll
            for (int r = 0; r < 4; ++r) {
                int m = quad * 4 + r;
                out[(row0 + m) * (OUT_T * ENC) + 255 * ENC + e] = accp[r] + ob;
            }
        }
    }
}

extern "C" void kernel_launch(void* const* d_in, const int* in_sizes, int n_in,
                              void* d_out, int out_size, void* d_ws, size_t ws_size,
                              hipStream_t stream) {
    const float* z    = (const float*)d_in[0];
    const float* hpw  = (const float*)d_in[1];
    const float* hpb  = (const float*)d_in[2];
    // d_in[3] = w_ih: unused by the reference (input gates are pure biases)
    const float* whh  = (const float*)d_in[4];
    const float* bih  = (const float*)d_in[5];
    const float* bhh  = (const float*)d_in[6];
    const float* outw = (const float*)d_in[7];
    const float* outb = (const float*)d_in[8];
    float* out = (float*)d_out;

    (void)d_ws; (void)ws_size;  // scratch lives in module .bss
    gru_fused<<<dim3(256), dim3(TPB), 0, stream>>>(
        z, hpw, hpb, whh, bih, bhh, outw, outb, out);
}

// Round 7
// 863.871 us; speedup vs baseline: 6.4420x; 1.9175x over previous
//
#include <hip/hip_runtime.h>

#define DM     512
#define LAT    128
#define WIN_   256
#define ENC    55
#define GB     32        // batch groups
#define BT     8         // batch rows per group
#define DS     64        // h-dims per slice
#define TPB    768       // 12 waves
#define OUT_T  256
#define AROWB  1056      // LDS bytes per staged h row (1024 data + 32 pad)
#define GHS    200       // ghT row stride in floats (192 data + 8 pad)
#define OWS    520       // sOutW row stride in u16 (512 data + 8 pad)

typedef __attribute__((ext_vector_type(8))) short bf8;
typedef __attribute__((ext_vector_type(4))) float f4;
typedef unsigned long long u64;
typedef unsigned short u16;

// .bss scratch: zero at load, not poisoned, no ws_size limit.
__device__ __align__(128) u64 g_ring[2 * 256 * 128];   // [slot][row][512] bf16
__device__ __align__(128) u64 g_flag[GB * 8 * 16];     // per (group,slice), 128 B apart

__device__ __forceinline__ u16 f2bf(float f) {
    union { float f; unsigned int i; } v; v.f = f;
    unsigned int r = v.i + 0x7fffu + ((v.i >> 16) & 1u);
    return (u16)(r >> 16);
}
__device__ __forceinline__ u64 pack4(float a, float b, float c, float d) {
    return (u64)f2bf(a) | ((u64)f2bf(b) << 16) | ((u64)f2bf(c) << 32) | ((u64)f2bf(d) << 48);
}
__device__ __forceinline__ float sigm(float x) { return 1.f / (1.f + __expf(-x)); }
__device__ __forceinline__ float tanh_(float x) {
    x = fminf(x, 40.f);
    float e = __expf(2.f * x);
    return (e - 1.f) / (e + 1.f);
}
#define ALOAD(p)     __hip_atomic_load((p),      __ATOMIC_RELAXED, __HIP_MEMORY_SCOPE_AGENT)
#define ASTORE(p, v) __hip_atomic_store((p), (v), __ATOMIC_RELAXED, __HIP_MEMORY_SCOPE_AGENT)

// Persistent fused GRU+projection, flag-based dataflow (no counter barrier).
// 256 blocks = 32 batch-groups x 8 d-slices. Per step:
//   wave 0     : gate math for own slice -> ring store -> vmcnt(0) -> flag=base+1+t
//   waves 1-7  : each polls ONE remote slice flag, stages 1 KB into LDS
//   all 12     : gate GEMM (16 MFMA) from staged tile vs resident w_hh fragments
//   waves 8-11 : projection vs LDS-resident bf16 out_w (1-in-8 steps per block)
// Flags are monotonic across launches (+257/launch); base = own flag at entry
// (race-free: nobody else writes it). Max inter-block skew is 1 step (ring
// depth 2), enforced by the flag dataflow itself -> no co-residency assumption.
__global__ __launch_bounds__(TPB, 3) void gru_fused(
    const float* __restrict__ z,    // [256][128]
    const float* __restrict__ hpw,  // [512][128]
    const float* __restrict__ hpb,  // [512]
    const float* __restrict__ whh,  // [1536][512]
    const float* __restrict__ bih,  // [1536]
    const float* __restrict__ bhh,  // [1536]
    const float* __restrict__ outw, // [55][512]
    const float* __restrict__ outb, // [55]
    float* __restrict__ out)        // [256][256][55] fp32
{
    const int blk  = blockIdx.x;
    const int g    = blk & (GB - 1);
    const int s    = blk >> 5;
    const int d0   = s * DS;
    const int row0 = g * BT;
    const int tid  = threadIdx.x;
    const int wave = tid >> 6;
    const int lane = tid & 63;
    const int quad = lane >> 4;
    const int nl   = lane & 15;

    __shared__ __align__(16) unsigned char smemA[BT * AROWB]; // staged h(t-1), bf16
    __shared__ __align__(16) float ghT[BT][GHS];              // [batch][gate*64+dim]
    __shared__ float bias_r[DS], bias_z[DS], gin_[DS], bhn_[DS];
    __shared__ __align__(16) float hprev[BT][DS];             // wave0-local fp32 h
    __shared__ __align__(16) float h0tmp[BT][DS];
    __shared__ __align__(16) u16 sOutW[ENC * OWS];            // bf16 out_w, padded
    __shared__ float sOutB[64];
    __shared__ u64 sh_base;

    u64* flag_own = g_flag + (u64)(g * 8 + s) * 16;
    if (tid == 0) sh_base = ALOAD(flag_own);

    if (tid < DS) {
        int dg = d0 + tid;
        bias_r[tid] = bih[dg]       + bhh[dg];
        bias_z[tid] = bih[512 + dg] + bhh[512 + dg];
        gin_[tid]   = bih[1024 + dg];
        bhn_[tid]   = bhh[1024 + dg];
    }
    if (tid < ENC) sOutB[tid] = outb[tid];
    for (int i = tid; i < ENC * DM; i += TPB)
        sOutW[(i >> 9) * OWS + (i & 511)] = f2bf(outw[i]);

    // Resident w_hh B-fragments: this wave's 16 gate rows x K=512.
    const int gl   = wave * 16 + nl;
    const int sel  = gl >> 6;
    const int jrow = sel * 512 + d0 + (gl & 63);
    bf8 bfrag[16];
#pragma unroll
    for (int kb = 0; kb < 16; ++kb) {
        const float* wp = whh + jrow * DM + kb * 32 + quad * 8;
        bf8 v;
#pragma unroll
        for (int j = 0; j < 8; ++j) v[j] = (short)f2bf(wp[j]);
        bfrag[kb] = v;
    }

    // h0 = tanh(z @ hpw^T + hpb)
    if (tid < BT * DS) {
        int d = tid & (DS - 1), bl = tid >> 6;
        float acc = hpb[d0 + d];
        const float* zr = z + (row0 + bl) * LAT;
        const float* wr = hpw + (d0 + d) * LAT;
#pragma unroll 8
        for (int k = 0; k < LAT; ++k) acc += zr[k] * wr[k];
        h0tmp[bl][d] = tanh_(acc);
    }
    __syncthreads();

    const u64 base = sh_base;
    const int prow = lane >> 3;        // wave-0 publish roles
    const int pdc  = (lane & 7) * 8;
    u64 pk0 = 0, pk1 = 0;

    if (wave == 0) {   // publish h(0): flag value base+1
        const float* hv = &h0tmp[prow][pdc];
        pk0 = pack4(hv[0], hv[1], hv[2], hv[3]);
        pk1 = pack4(hv[4], hv[5], hv[6], hv[7]);
        *(f4*)&hprev[prow][pdc]     = *(const f4*)&h0tmp[prow][pdc];
        *(f4*)&hprev[prow][pdc + 4] = *(const f4*)&h0tmp[prow][pdc + 4];
        u64* dst = g_ring + (u64)(row0 + prow) * 128 + (d0 >> 2) + (lane & 7) * 2;
        ASTORE(dst, pk0);
        ASTORE(dst + 1, pk1);
        asm volatile("s_waitcnt vmcnt(0)" ::: "memory");
        if (lane == 0) ASTORE(flag_own, base + 1);
    }

    const char* afrag_p = (const char*)smemA + (nl & 7) * AROWB + quad * 16;

    for (int t = 1; t <= WIN_; ++t) {
        const int sp = (t - 1) & 1, sc = t & 1;

        // ---- stage h(t-1) into smemA ----
        if (wave == 0) {
            char* dp = (char*)smemA + prow * AROWB + (d0 + pdc) * 2;
            *(u64*)dp = pk0; *(u64*)(dp + 8) = pk1;
        } else if (wave < 8) {
            const int j = (s + wave) & 7;
            u64* fp = g_flag + (u64)(g * 8 + j) * 16;
            const u64 want = base + t;           // flag for h(t-1)
            long guard = 0;
            while (ALOAD(fp) < want && guard < (1L << 20)) ++guard;
            asm volatile("" ::: "memory");       // no hoisting of data loads
            const u64* src = g_ring + (u64)(sp * 256 + row0 + prow) * 128
                             + j * 16 + (lane & 7) * 2;
            u64 lo = ALOAD(src), hi = ALOAD(src + 1);
            char* dp = (char*)smemA + prow * AROWB + j * 128 + (lane & 7) * 16;
            *(u64*)dp = lo; *(u64*)(dp + 8) = hi;
        }
        __syncthreads();  // A: tile complete

        // ---- gate GEMM: 192 rows x K=512 ----
        f4 acc = {0.f, 0.f, 0.f, 0.f};
#pragma unroll
        for (int kb = 0; kb < 16; ++kb) {
            bf8 av = *(const bf8*)(afrag_p + kb * 64);
            acc = __builtin_amdgcn_mfma_f32_16x16x32_bf16(av, bfrag[kb], acc, 0, 0, 0);
        }
        if (quad < 2) {
            const int c = sel * 64 + (gl & 63);
#pragma unroll
            for (int r = 0; r < 4; ++r) ghT[quad * 4 + r][c] = acc[r];
        }
        __syncthreads();  // B: ghT complete

        // ---- wave 0: gate update + publish (group-critical path) ----
        if (wave == 0) {
            const float* grow = &ghT[prow][0];
            f4 hp0 = *(const f4*)&hprev[prow][pdc];
            f4 hp1 = *(const f4*)&hprev[prow][pdc + 4];
            float hn[8];
#pragma unroll
            for (int j = 0; j < 8; ++j) {
                int d = pdc + j;
                float rr = sigm(bias_r[d] + grow[d]);
                float zg = sigm(bias_z[d] + grow[64 + d]);
                float nn = tanh_(gin_[d] + rr * (bhn_[d] + grow[128 + d]));
                float hpj = (j < 4) ? hp0[j] : hp1[j - 4];
                hn[j] = (1.f - zg) * nn + zg * hpj;
            }
            pk0 = pack4(hn[0], hn[1], hn[2], hn[3]);
            pk1 = pack4(hn[4], hn[5], hn[6], hn[7]);
            f4 w0 = {hn[0], hn[1], hn[2], hn[3]}, w1 = {hn[4], hn[5], hn[6], hn[7]};
            *(f4*)&hprev[prow][pdc] = w0;
            *(f4*)&hprev[prow][pdc + 4] = w1;
            u64* dst = g_ring + (u64)(sc * 256 + row0 + prow) * 128 + (d0 >> 2) + (lane & 7) * 2;
            ASTORE(dst, pk0);
            ASTORE(dst + 1, pk1);
            asm volatile("s_waitcnt vmcnt(0)" ::: "memory");
            if (lane == 0) ASTORE(flag_own, base + 1 + t);
        }

        // ---- waves 8-11: fused projection out[:,tau,:] from smemA (h(t-1)) ----
        const int tau = t - 2;
        const bool proj = (tau >= 0) && ((tau & 7) == s);
        if (proj && wave >= 8) {
            const int e  = (wave - 8) * 16 + nl;
            const int ec = (e < ENC) ? e : (ENC - 1);
            const u16* wrow = sOutW + ec * OWS + quad * 8;
            f4 accp = {0.f, 0.f, 0.f, 0.f};
#pragma unroll
            for (int kb = 0; kb < 16; ++kb) {
                bf8 av = *(const bf8*)(afrag_p + kb * 64);
                bf8 wv = *(const bf8*)(wrow + kb * 32);
                accp = __builtin_amdgcn_mfma_f32_16x16x32_bf16(av, wv, accp, 0, 0, 0);
            }
            if (quad < 2 && e < ENC) {
                float ob = sOutB[e];
#pragma unroll
                for (int r = 0; r < 4; ++r) {
                    int m = quad * 4 + r;
                    out[(row0 + m) * (OUT_T * ENC) + tau * ENC + e] = accp[r] + ob;
                }
            }
        }
        // C: only needed when smemA had post-B readers (projection steps);
        // condition is block-uniform so the barrier is valid.
        if (proj) __syncthreads();
    }

    // ---- tail: tau=255 ((255&7)==7) uses h(256) (slot 0, flag base+257) ----
    if (s == 7) {
        if (wave == 0) {
            char* dp = (char*)smemA + prow * AROWB + (d0 + pdc) * 2;
            *(u64*)dp = pk0; *(u64*)(dp + 8) = pk1;
        } else if (wave < 8) {
            const int j = (s + wave) & 7;
            u64* fp = g_flag + (u64)(g * 8 + j) * 16;
            const u64 want = base + 1 + WIN_;
            long guard = 0;
            while (ALOAD(fp) < want && guard < (1L << 20)) ++guard;
            asm volatile("" ::: "memory");
            const u64* src = g_ring + (u64)(row0 + prow) * 128 + j * 16 + (lane & 7) * 2;
            u64 lo = ALOAD(src), hi = ALOAD(src + 1);
            char* dp = (char*)smemA + prow * AROWB + j * 128 + (lane & 7) * 16;
            *(u64*)dp = lo; *(u64*)(dp + 8) = hi;
        }
        __syncthreads();
        if (wave >= 8) {
            const int e  = (wave - 8) * 16 + nl;
            const int ec = (e < ENC) ? e : (ENC - 1);
            const u16* wrow = sOutW + ec * OWS + quad * 8;
            f4 accp = {0.f, 0.f, 0.f, 0.f};
#pragma unroll
            for (int kb = 0; kb < 16; ++kb) {
                bf8 av = *(const bf8*)(afrag_p + kb * 64);
                bf8 wv = *(const bf8*)(wrow + kb * 32);
                accp = __builtin_amdgcn_mfma_f32_16x16x32_bf16(av, wv, accp, 0, 0, 0);
            }
            if (quad < 2 && e < ENC) {
                float ob = sOutB[e];
#pragma unroll
                for (int r = 0; r < 4; ++r) {
                    int m = quad * 4 + r;
                    out[(row0 + m) * (OUT_T * ENC) + 255 * ENC + e] = accp[r] + ob;
                }
            }
        }
    }
}

extern "C" void kernel_launch(void* const* d_in, const int* in_sizes, int n_in,
                              void* d_out, int out_size, void* d_ws, size_t ws_size,
                              hipStream_t stream) {
    const float* z    = (const float*)d_in[0];
    const float* hpw  = (const float*)d_in[1];
    const float* hpb  = (const float*)d_in[2];
    // d_in[3] = w_ih: unused by the reference (input gates are pure biases)
    const float* whh  = (const float*)d_in[4];
    const float* bih  = (const float*)d_in[5];
    const float* bhh  = (const float*)d_in[6];
    const float* outw = (const float*)d_in[7];
    const float* outb = (const float*)d_in[8];
    float* out = (float*)d_out;

    (void)d_ws; (void)ws_size;  // scratch lives in module .bss
    gru_fused<<<dim3(256), dim3(TPB), 0, stream>>>(
        z, hpw, hpb, whh, bih, bhh, outw, outb, out);
}